// Round 20
// baseline (147.639 us; speedup 1.0000x reference)
//
#include <hip/hip_runtime.h>
#include <cstdint>
#include <cstddef>

#define N_NODES 100000
#define E_EDGES 1600000
#define F_IN 256
#define F_OUT 128
#define NBKT 391      // ceil(N_NODES/256) buckets of 256 nodes
#define OBCAP 5120    // per-bucket LDS sort capacity
#define GEMM_NB 1563  // ceil(N_NODES/64)
#define WCVT_NB 128   // 32768/256
#define HSTR 400      // HIST row stride (ints)

#define GLOBAL_AS __attribute__((address_space(1)))
#define LDS_AS    __attribute__((address_space(3)))

typedef __attribute__((ext_vector_type(8))) short  short8v;
typedef __attribute__((ext_vector_type(4))) float  float4v;

__device__ __forceinline__ unsigned short f2bf(float x) {
    union { float f; unsigned u; } v; v.f = x;
    unsigned r = v.u + 0x7fffu + ((v.u >> 16) & 1u);   // RNE
    return (unsigned short)(r >> 16);
}

__device__ __forceinline__ unsigned cvt_pk_bf16(float lo, float hi) {
    unsigned r;
    asm("v_cvt_pk_bf16_f32 %0, %1, %2" : "=v"(r) : "v"(lo), "v"(hi));
    return r;
}

// ---------------- fused: W transpose+convert (blocks 0..127) + dst histogram ----------------
__global__ __launch_bounds__(256) void wcvt_hist(const float* __restrict__ W,
                                                 unsigned short* __restrict__ Wt,
                                                 const int* __restrict__ dst,
                                                 int* __restrict__ bcnt,
                                                 int* __restrict__ hist) {
    __shared__ int h[NBKT];
    int t = threadIdx.x;
    if (blockIdx.x < WCVT_NB) {
        int i = blockIdx.x * 256 + t;
        int k = i >> 7, j = i & 127;
        Wt[j * F_IN + k] = f2bf(W[i]);
        return;
    }
    int b = blockIdx.x - WCVT_NB;
    for (int i = t; i < NBKT; i += 256) h[i] = 0;
    __syncthreads();
    int e0  = b * 4096;
    int end = min(e0 + 4096, E_EDGES);
    for (int i = e0 + t; i < end; i += 256) atomicAdd(&h[dst[i] >> 8], 1);
    __syncthreads();
    for (int i = t; i < NBKT; i += 256) {
        int c = h[i];
        hist[b * HSTR + i] = c;                 // coalesced row write
        if (c) atomicAdd(&bcnt[i], c);
    }
}

// ---------------- per-bucket offset scan: HIST[b][i] -> absolute scatter offsets ----------------
__global__ __launch_bounds__(512) void k_scan2(const int* __restrict__ bcnt,
                                               int* __restrict__ bbase,
                                               int* __restrict__ hist) {
    __shared__ int s[512];
    __shared__ int base_sh;
    int t = threadIdx.x;
    int i = blockIdx.x;                         // bucket
    int d = (t < NBKT) ? bcnt[t] : 0;
    s[t] = d;
    __syncthreads();
    for (int off = 1; off < 512; off <<= 1) {
        int v = (t >= off) ? s[t - off] : 0;
        __syncthreads();
        s[t] += v;
        __syncthreads();
    }
    if (t == 0) {
        int bi = (i > 0) ? s[i - 1] : 0;
        base_sh = bi;
        bbase[i] = bi;
        if (i == NBKT - 1) bbase[NBKT] = s[NBKT - 1];
    }
    __syncthreads();
    int base_i = base_sh;
    int hv = (t < NBKT) ? hist[t * HSTR + i] : 0;
    __syncthreads();
    s[t] = hv;
    __syncthreads();
    for (int off = 1; off < 512; off <<= 1) {
        int v = (t >= off) ? s[t - off] : 0;
        __syncthreads();
        s[t] += v;
        __syncthreads();
    }
    if (t < NBKT) hist[t * HSTR + i] = s[t] - hv + base_i;
}

// ---------------- fused: MFMA GEMM (blocks 0..1562, BK=32, 16KB LDS) + scatter ----------------
// 16KB LDS -> 8 blocks/CU (wave-slot cap): entire 1954-block grid co-resident,
// maximizing block-level TLP to hide the staging drains.
__global__ __launch_bounds__(256) void gemm_scatter(const float* __restrict__ A,
                                                    const unsigned short* __restrict__ Wt,
                                                    const float* __restrict__ attn_l,
                                                    const float* __restrict__ attn_r,
                                                    unsigned short* __restrict__ Hb,
                                                    float* __restrict__ el,
                                                    float* __restrict__ er,
                                                    const int* __restrict__ src,
                                                    const int* __restrict__ dst,
                                                    const int* __restrict__ hist,
                                                    unsigned int* __restrict__ epack) {
    __shared__ __align__(16) char smem[16 * 1024];   // gemm: 8KB A + 8KB B ; scatter: h[NBKT]
    int tid = threadIdx.x;

    if (blockIdx.x >= GEMM_NB) {
        // ---- level-1 scatter with precomputed offsets ----
        int* h = (int*)smem;
        int b = blockIdx.x - GEMM_NB;
        for (int i = tid; i < NBKT; i += 256) h[i] = hist[b * HSTR + i];
        __syncthreads();
        int e0  = b * 4096;
        int end = min(e0 + 4096, E_EDGES);
        #pragma unroll
        for (int j = 0; j < 16; ++j) {
            int i = e0 + j * 256 + tid;
            if (i < end) {
                int dv = dst[i];
                int p = atomicAdd(&h[dv >> 8], 1);           // LDS atomic only
                epack[p] = (unsigned)src[i] | ((unsigned)(dv & 255) << 17);
            }
        }
        return;
    }

    // ---- MFMA GEMM + fused el/er + bf16 H store (BK=32, single-buffered) ----
    float*          Afs = (float*)smem;                       // 64 x 32 f32  = 8KB
    unsigned short* Bs  = (unsigned short*)(smem + 8192);     // 128 x 32 bf16 = 8KB
    int wave = tid >> 6, lane = tid & 63;
    int g = lane >> 4, c = lane & 15;
    int row0 = blockIdx.x * 64;
    float4v acc[8] = {};

    int a_w[2], a_r[2], a_k[2];
    #pragma unroll
    for (int i = 0; i < 2; ++i) {
        int W_ = i * 1024 + tid * 4;            // word slot in 2048-word A buffer
        int r  = W_ >> 5;                       // 32 words/row
        a_w[i] = W_;
        a_r[i] = min(row0 + r, N_NODES - 1);
        a_k[i] = (W_ & 31) ^ ((r & 7) << 2);    // inverse-swizzled source k
    }
    int b_u[2], b_j[2], b_k[2];
    #pragma unroll
    for (int i = 0; i < 2; ++i) {
        int U_ = i * 2048 + tid * 8;            // ushort slot in 4096-ushort B buffer
        int j  = U_ >> 5;                       // 32 ushorts/row
        b_u[i] = U_;
        b_j[i] = j;
        b_k[i] = (U_ & 31) ^ ((j & 3) << 3);
    }

    int arow = wave * 16 + c;
    int aswz = (arow & 7) << 2;
    int woff = arow * 32 + g * 8;

    for (int k0 = 0; k0 < F_IN; k0 += 32) {
        #pragma unroll
        for (int i = 0; i < 2; ++i) {
            __builtin_amdgcn_global_load_lds(
                (const GLOBAL_AS unsigned int*)(A + (size_t)a_r[i] * F_IN + k0 + a_k[i]),
                (LDS_AS unsigned int*)&Afs[a_w[i]], 16, 0, 0);
        }
        #pragma unroll
        for (int i = 0; i < 2; ++i) {
            __builtin_amdgcn_global_load_lds(
                (const GLOBAL_AS unsigned int*)(Wt + (size_t)b_j[i] * F_IN + k0 + b_k[i]),
                (LDS_AS unsigned int*)&Bs[b_u[i]], 16, 0, 0);
        }
        __syncthreads();
        {
            float4 a0 = *reinterpret_cast<float4*>(&Afs[(woff)     ^ aswz]);
            float4 a1 = *reinterpret_cast<float4*>(&Afs[(woff + 4) ^ aswz]);
            unsigned u[4];
            u[0] = cvt_pk_bf16(a0.x, a0.y);
            u[1] = cvt_pk_bf16(a0.z, a0.w);
            u[2] = cvt_pk_bf16(a1.x, a1.y);
            u[3] = cvt_pk_bf16(a1.z, a1.w);
            short8v af = *reinterpret_cast<short8v*>(u);
            #pragma unroll
            for (int nt = 0; nt < 8; ++nt) {
                int j = nt * 16 + c;
                int boff = j * 32 + ((g * 8) ^ ((j & 3) << 3));
                short8v bf = *reinterpret_cast<short8v*>(&Bs[boff]);
                acc[nt] = __builtin_amdgcn_mfma_f32_16x16x32_bf16(af, bf, acc[nt], 0, 0, 0);
            }
        }
        __syncthreads();
    }

    float al[8], ar[8];
    #pragma unroll
    for (int nt = 0; nt < 8; ++nt) {
        al[nt] = attn_l[nt * 16 + c];
        ar[nt] = attn_r[nt * 16 + c];
    }
    #pragma unroll
    for (int r = 0; r < 4; ++r) {
        int grow = row0 + wave * 16 + g * 4 + r;
        float sl = 0.f, sr = 0.f;
        #pragma unroll
        for (int nt = 0; nt < 8; ++nt) {
            float h = acc[nt][r];
            sl += h * al[nt];
            sr += h * ar[nt];
        }
        if (grow < N_NODES) {
            #pragma unroll
            for (int nt = 0; nt < 8; ++nt)
                Hb[(size_t)grow * F_OUT + nt * 16 + c] = f2bf(acc[nt][r]);
        }
        #pragma unroll
        for (int off = 1; off < 16; off <<= 1) {
            sl += __shfl_xor(sl, off);
            sr += __shfl_xor(sr, off);
        }
        if (c == 0 && grow < N_NODES) { el[grow] = sl; er[grow] = sr; }
    }
}

// ---------------- level-2: per-bucket sort + edge softmax -> normalized (alpha, rowb) ----------------
__global__ __launch_bounds__(256) void k_sort2(const unsigned int* __restrict__ epack,
                                               const int* __restrict__ bbase,
                                               const float* __restrict__ el,
                                               const float* __restrict__ er,
                                               float2* __restrict__ exs,
                                               int* __restrict__ rowptr,
                                               int* __restrict__ deg) {
    __shared__ int hist[256], cur[256], s[256];
    __shared__ float ssl[256];
    __shared__ unsigned obuf[OBCAP];
    __shared__ float exb[OBCAP];
    int b = blockIdx.x, t = threadIdx.x;
    int base = bbase[b], end = bbase[b + 1];
    int cnt  = end - base;
    hist[t] = 0;
    ssl[t] = 0.f;
    __syncthreads();
    for (int i = t; i < cnt; i += 256) atomicAdd(&hist[epack[base + i] >> 17], 1);
    __syncthreads();
    int d = hist[t];
    s[t] = d;
    __syncthreads();
    for (int off = 1; off < 256; off <<= 1) {
        int v = (t >= off) ? s[t - off] : 0;
        __syncthreads();
        s[t] += v;
        __syncthreads();
    }
    int excl = s[t] - d;
    int n = b * 256 + t;
    if (n < N_NODES) { deg[n] = d; rowptr[n] = base + excl; }
    cur[t] = excl;
    __syncthreads();
    for (int i = t; i < cnt; i += 256) {
        unsigned e = epack[base + i];
        int d2  = e >> 17;
        int sid = (int)(e & 0x1FFFFu);
        float tv = el[sid] + er[b * 256 + d2];
        tv = tv > 0.f ? tv : 0.2f * tv;       // leaky_relu; |tv| small -> exp exact-safe
        float ex = __expf(tv);
        int p = atomicAdd(&cur[d2], 1);
        if (p < OBCAP) { obuf[p] = e; exb[p] = ex; }
        atomicAdd(&ssl[d2], ex);
    }
    __syncthreads();
    for (int i = t; i < cnt; i += 256) {
        unsigned e = obuf[i];
        float alpha = exb[i] / ssl[e >> 17];
        exs[base + i] = make_float2(alpha, __uint_as_float((e & 0x1FFFFu) << 8));
    }
}

// ---------------- fused: normalized aggregation + head ----------------
__global__ __launch_bounds__(256) void agg_fused(const int* __restrict__ rowptr,
                                                 const int* __restrict__ deg,
                                                 const float2* __restrict__ exs,
                                                 const char* __restrict__ Hc,
                                                 const float* __restrict__ bias,
                                                 const float* __restrict__ fcw,
                                                 const float* __restrict__ fcb,
                                                 float* __restrict__ out) {
    __shared__ float2 exbuf[4][64];
    int tid   = threadIdx.x;
    int wslot = tid >> 6;
    int wid   = (blockIdx.x * 256 + tid) >> 6;
    int lane  = tid & 63;
    if (wid >= N_NODES) return;
    int grp = lane >> 4, fl = lane & 15;
    int start = rowptr[wid];
    int dg    = deg[wid];
    float acc[8] = {};
    float2* eb = exbuf[wslot];
    unsigned flb = (unsigned)fl << 4;

    for (int base = 0; base < dg; base += 64) {
        int cnt = min(64, dg - base);
        float2 p2 = make_float2(0.f, 0.f);     // alpha=0, row 0 -> harmless pad
        if (lane < cnt) p2 = exs[start + base + lane];
        eb[lane] = p2;
        __builtin_amdgcn_wave_barrier();
        int nq = (cnt + 3) >> 2;
        #pragma unroll 2
        for (int q = 0; q < nq; ++q) {
            float2 p = eb[q * 4 + grp];
            float aq = p.x;
            uint4 v = *(const uint4*)(Hc + (__float_as_uint(p.y) + flb));
            acc[0] += aq * __uint_as_float(v.x << 16);
            acc[1] += aq * __uint_as_float(v.x & 0xffff0000u);
            acc[2] += aq * __uint_as_float(v.y << 16);
            acc[3] += aq * __uint_as_float(v.y & 0xffff0000u);
            acc[4] += aq * __uint_as_float(v.z << 16);
            acc[5] += aq * __uint_as_float(v.z & 0xffff0000u);
            acc[6] += aq * __uint_as_float(v.w << 16);
            acc[7] += aq * __uint_as_float(v.w & 0xffff0000u);
        }
        __builtin_amdgcn_wave_barrier();
    }

    #pragma unroll
    for (int j = 0; j < 8; ++j) {
        acc[j] += __shfl_xor(acc[j], 16);
        acc[j] += __shfl_xor(acc[j], 32);
    }

    float4 b0 = ((const float4*)bias)[fl * 2];
    float4 b1 = ((const float4*)bias)[fl * 2 + 1];
    float d0 = 0.f, d1 = 0.f;
    #pragma unroll
    for (int j = 0; j < 8; ++j) {
        float bj = j < 4 ? (&b0.x)[j] : (&b1.x)[j - 4];
        float vv = fmaxf(acc[j] + bj, 0.f);
        float2 wj = ((const float2*)fcw)[fl * 8 + j];
        d0 += vv * wj.x;
        d1 += vv * wj.y;
    }
    #pragma unroll
    for (int off = 1; off < 16; off <<= 1) {
        d0 += __shfl_xor(d0, off);
        d1 += __shfl_xor(d1, off);
    }
    if (lane == 0) {
        out[(size_t)wid * 2 + 0] = 1.f / (1.f + __expf(-(d0 + fcb[0])));
        out[(size_t)wid * 2 + 1] = 1.f / (1.f + __expf(-(d1 + fcb[1])));
    }
}

extern "C" void kernel_launch(void* const* d_in, const int* in_sizes, int n_in,
                              void* d_out, int out_size, void* d_ws, size_t ws_size,
                              hipStream_t stream) {
    const float* in_feat = (const float*)d_in[0];
    const float* W       = (const float*)d_in[1];
    const float* attn_l  = (const float*)d_in[2];
    const float* attn_r  = (const float*)d_in[3];
    const float* bias    = (const float*)d_in[4];
    const float* fc_w    = (const float*)d_in[5];
    const float* fc_b    = (const float*)d_in[6];
    const int*   src     = (const int*)d_in[7];
    const int*   dst     = (const int*)d_in[8];
    float* out = (float*)d_out;

    char* p = (char*)d_ws;
    unsigned short* HB = (unsigned short*)p; p += (size_t)N_NODES * F_OUT * sizeof(unsigned short);
    unsigned short* WT = (unsigned short*)p; p += (size_t)F_IN * F_OUT * sizeof(unsigned short);
    float* EL     = (float*)p; p += (size_t)N_NODES * sizeof(float);
    float* ER     = (float*)p; p += (size_t)N_NODES * sizeof(float);
    int*   DEG    = (int*)p;   p += (size_t)N_NODES * sizeof(int);
    int*   ROWPTR = (int*)p;   p += (size_t)N_NODES * sizeof(int);
    int*   BCNT   = (int*)p;   p += 512 * sizeof(int);
    int*   BBASE  = (int*)p;   p += 512 * sizeof(int);
    int*   HIST   = (int*)p;   p += (size_t)NBKT * HSTR * sizeof(int);
    unsigned int* EPACK = (unsigned int*)p; p += (size_t)E_EDGES * sizeof(unsigned int);
    float2* EXS   = (float2*)p; p += (size_t)E_EDGES * sizeof(float2);

    hipMemsetAsync(BCNT, 0, 512 * sizeof(int), stream);

    wcvt_hist<<<WCVT_NB + NBKT, 256, 0, stream>>>(W, WT, dst, BCNT, HIST);
    k_scan2  <<<NBKT, 512, 0, stream>>>(BCNT, BBASE, HIST);
    gemm_scatter<<<GEMM_NB + NBKT, 256, 0, stream>>>(
        in_feat, WT, attn_l, attn_r, HB, EL, ER, src, dst, HIST, EPACK);
    k_sort2  <<<NBKT, 256, 0, stream>>>(EPACK, BBASE, EL, ER, EXS, ROWPTR, DEG);

    agg_fused<<<(N_NODES * 64 + 255) / 256, 256, 0, stream>>>(
        ROWPTR, DEG, EXS, (const char*)HB, bias, fc_w, fc_b, out);
}

// Round 21
// 145.715 us; speedup vs baseline: 1.0132x; 1.0132x over previous
//
#include <hip/hip_runtime.h>
#include <cstdint>
#include <cstddef>

#define N_NODES 100000
#define E_EDGES 1600000
#define F_IN 256
#define F_OUT 128
#define NBKT 391      // ceil(N_NODES/256) buckets of 256 nodes
#define OBCAP 5120    // per-bucket LDS sort capacity
#define GEMM_NB 1563  // ceil(N_NODES/64)
#define WCVT_NB 128   // 32768/256
#define HSTR 400      // HIST row stride (ints)

#define GLOBAL_AS __attribute__((address_space(1)))
#define LDS_AS    __attribute__((address_space(3)))

typedef __attribute__((ext_vector_type(8))) short  short8v;
typedef __attribute__((ext_vector_type(4))) float  float4v;

__device__ __forceinline__ unsigned short f2bf(float x) {
    union { float f; unsigned u; } v; v.f = x;
    unsigned r = v.u + 0x7fffu + ((v.u >> 16) & 1u);   // RNE
    return (unsigned short)(r >> 16);
}

__device__ __forceinline__ unsigned cvt_pk_bf16(float lo, float hi) {
    unsigned r;
    asm("v_cvt_pk_bf16_f32 %0, %1, %2" : "=v"(r) : "v"(lo), "v"(hi));
    return r;
}

// ---------------- fused: W transpose+convert (blocks 0..127) + dst histogram ----------------
__global__ __launch_bounds__(256) void wcvt_hist(const float* __restrict__ W,
                                                 unsigned short* __restrict__ Wt,
                                                 const int* __restrict__ dst,
                                                 int* __restrict__ bcnt,
                                                 int* __restrict__ hist) {
    __shared__ int h[NBKT];
    int t = threadIdx.x;
    if (blockIdx.x < WCVT_NB) {
        int i = blockIdx.x * 256 + t;
        int k = i >> 7, j = i & 127;
        Wt[j * F_IN + k] = f2bf(W[i]);
        return;
    }
    int b = blockIdx.x - WCVT_NB;
    for (int i = t; i < NBKT; i += 256) h[i] = 0;
    __syncthreads();
    int e0  = b * 4096;
    int end = min(e0 + 4096, E_EDGES);
    for (int i = e0 + t; i < end; i += 256) atomicAdd(&h[dst[i] >> 8], 1);
    __syncthreads();
    for (int i = t; i < NBKT; i += 256) {
        int c = h[i];
        hist[b * HSTR + i] = c;                 // coalesced row write
        if (c) atomicAdd(&bcnt[i], c);
    }
}

// ---------------- per-bucket offset scan: HIST[b][i] -> absolute scatter offsets ----------------
__global__ __launch_bounds__(512) void k_scan2(const int* __restrict__ bcnt,
                                               int* __restrict__ bbase,
                                               int* __restrict__ hist) {
    __shared__ int s[512];
    __shared__ int base_sh;
    int t = threadIdx.x;
    int i = blockIdx.x;                         // bucket
    int d = (t < NBKT) ? bcnt[t] : 0;
    s[t] = d;
    __syncthreads();
    for (int off = 1; off < 512; off <<= 1) {
        int v = (t >= off) ? s[t - off] : 0;
        __syncthreads();
        s[t] += v;
        __syncthreads();
    }
    if (t == 0) {
        int bi = (i > 0) ? s[i - 1] : 0;
        base_sh = bi;
        bbase[i] = bi;
        if (i == NBKT - 1) bbase[NBKT] = s[NBKT - 1];
    }
    __syncthreads();
    int base_i = base_sh;
    int hv = (t < NBKT) ? hist[t * HSTR + i] : 0;
    __syncthreads();
    s[t] = hv;
    __syncthreads();
    for (int off = 1; off < 512; off <<= 1) {
        int v = (t >= off) ? s[t - off] : 0;
        __syncthreads();
        s[t] += v;
        __syncthreads();
    }
    if (t < NBKT) hist[t * HSTR + i] = s[t] - hv + base_i;
}

// ---------------- fused: MFMA GEMM (blocks 0..1562) + level-1 scatter (no atomics) ----------------
__global__ __launch_bounds__(256) void gemm_scatter(const float* __restrict__ A,
                                                    const unsigned short* __restrict__ Wt,
                                                    const float* __restrict__ attn_l,
                                                    const float* __restrict__ attn_r,
                                                    unsigned short* __restrict__ Hb,
                                                    float* __restrict__ el,
                                                    float* __restrict__ er,
                                                    const int* __restrict__ src,
                                                    const int* __restrict__ dst,
                                                    const int* __restrict__ hist,
                                                    unsigned int* __restrict__ epack) {
    __shared__ char smem[32 * 1024];     // gemm: 16KB Afs + 16KB Bs ; scatter: h[NBKT]
    int tid = threadIdx.x;

    if (blockIdx.x >= GEMM_NB) {
        // ---- level-1 scatter with precomputed offsets ----
        int* h = (int*)smem;
        int b = blockIdx.x - GEMM_NB;
        for (int i = tid; i < NBKT; i += 256) h[i] = hist[b * HSTR + i];
        __syncthreads();
        int e0  = b * 4096;
        int end = min(e0 + 4096, E_EDGES);
        #pragma unroll
        for (int j = 0; j < 16; ++j) {
            int i = e0 + j * 256 + tid;
            if (i < end) {
                int dv = dst[i];
                int p = atomicAdd(&h[dv >> 8], 1);           // LDS atomic only
                epack[p] = (unsigned)src[i] | ((unsigned)(dv & 255) << 17);
            }
        }
        return;
    }

    // ---- MFMA GEMM + fused el/er + bf16 H store ----
    float*          Afs = (float*)smem;
    unsigned short* Bs  = (unsigned short*)(smem + 16 * 1024);
    int wave = tid >> 6, lane = tid & 63;
    int g = lane >> 4, c = lane & 15;
    int row0 = blockIdx.x * 64;
    float4v acc[8] = {};

    int a_r[4], a_k[4], a_w[4];
    #pragma unroll
    for (int i = 0; i < 4; ++i) {
        int W_ = i * 1024 + tid * 4;
        int r  = W_ >> 6;
        a_w[i] = W_;
        a_r[i] = min(row0 + r, N_NODES - 1);
        a_k[i] = (W_ & 63) ^ ((r & 15) << 2);
    }
    int b_j[4], b_k[4], b_u[4];
    #pragma unroll
    for (int i = 0; i < 4; ++i) {
        int U_ = i * 2048 + tid * 8;
        int j  = U_ >> 6;
        b_u[i] = U_;
        b_j[i] = j;
        b_k[i] = (U_ & 63) ^ ((j & 7) << 3);
    }

    for (int k0 = 0; k0 < F_IN; k0 += 64) {
        #pragma unroll
        for (int i = 0; i < 4; ++i) {
            __builtin_amdgcn_global_load_lds(
                (const GLOBAL_AS unsigned int*)(A + (size_t)a_r[i] * F_IN + k0 + a_k[i]),
                (LDS_AS unsigned int*)&Afs[a_w[i]], 16, 0, 0);
        }
        #pragma unroll
        for (int i = 0; i < 4; ++i) {
            __builtin_amdgcn_global_load_lds(
                (const GLOBAL_AS unsigned int*)(Wt + (size_t)b_j[i] * F_IN + k0 + b_k[i]),
                (LDS_AS unsigned int*)&Bs[b_u[i]], 16, 0, 0);
        }
        __syncthreads();
        int arow = wave * 16 + c;
        int aswz = (arow & 15) << 2;
        #pragma unroll
        for (int ks = 0; ks < 2; ++ks) {
            int woff = arow * 64 + ks * 32 + g * 8;
            float4 a0 = *reinterpret_cast<float4*>(&Afs[(woff)     ^ aswz]);
            float4 a1 = *reinterpret_cast<float4*>(&Afs[(woff + 4) ^ aswz]);
            unsigned u[4];
            u[0] = cvt_pk_bf16(a0.x, a0.y);
            u[1] = cvt_pk_bf16(a0.z, a0.w);
            u[2] = cvt_pk_bf16(a1.x, a1.y);
            u[3] = cvt_pk_bf16(a1.z, a1.w);
            short8v af = *reinterpret_cast<short8v*>(u);
            #pragma unroll
            for (int nt = 0; nt < 8; ++nt) {
                int j = nt * 16 + c;
                int boff = (j * 64 + ks * 32 + g * 8) ^ ((j & 7) << 3);
                short8v bf = *reinterpret_cast<short8v*>(&Bs[boff]);
                acc[nt] = __builtin_amdgcn_mfma_f32_16x16x32_bf16(af, bf, acc[nt], 0, 0, 0);
            }
        }
        __syncthreads();
    }

    float al[8], ar[8];
    #pragma unroll
    for (int nt = 0; nt < 8; ++nt) {
        al[nt] = attn_l[nt * 16 + c];
        ar[nt] = attn_r[nt * 16 + c];
    }
    #pragma unroll
    for (int r = 0; r < 4; ++r) {
        int grow = row0 + wave * 16 + g * 4 + r;
        float sl = 0.f, sr = 0.f;
        #pragma unroll
        for (int nt = 0; nt < 8; ++nt) {
            float h = acc[nt][r];
            sl += h * al[nt];
            sr += h * ar[nt];
        }
        if (grow < N_NODES) {
            #pragma unroll
            for (int nt = 0; nt < 8; ++nt)
                Hb[(size_t)grow * F_OUT + nt * 16 + c] = f2bf(acc[nt][r]);
        }
        #pragma unroll
        for (int off = 1; off < 16; off <<= 1) {
            sl += __shfl_xor(sl, off);
            sr += __shfl_xor(sr, off);
        }
        if (c == 0 && grow < N_NODES) { el[grow] = sl; er[grow] = sr; }
    }
}

// ---------------- level-2: per-bucket sort + edge softmax -> normalized (alpha, rowb) ----------------
__global__ __launch_bounds__(256) void k_sort2(const unsigned int* __restrict__ epack,
                                               const int* __restrict__ bbase,
                                               const float* __restrict__ el,
                                               const float* __restrict__ er,
                                               float2* __restrict__ exs,
                                               int* __restrict__ rowptr,
                                               int* __restrict__ deg) {
    __shared__ int hist[256], cur[256], s[256];
    __shared__ float ssl[256];
    __shared__ unsigned obuf[OBCAP];
    __shared__ float exb[OBCAP];
    int b = blockIdx.x, t = threadIdx.x;
    int base = bbase[b], end = bbase[b + 1];
    int cnt  = end - base;
    hist[t] = 0;
    ssl[t] = 0.f;
    __syncthreads();
    for (int i = t; i < cnt; i += 256) atomicAdd(&hist[epack[base + i] >> 17], 1);
    __syncthreads();
    int d = hist[t];
    s[t] = d;
    __syncthreads();
    for (int off = 1; off < 256; off <<= 1) {
        int v = (t >= off) ? s[t - off] : 0;
        __syncthreads();
        s[t] += v;
        __syncthreads();
    }
    int excl = s[t] - d;
    int n = b * 256 + t;
    if (n < N_NODES) { deg[n] = d; rowptr[n] = base + excl; }
    cur[t] = excl;
    __syncthreads();
    for (int i = t; i < cnt; i += 256) {
        unsigned e = epack[base + i];
        int d2  = e >> 17;
        int sid = (int)(e & 0x1FFFFu);
        float tv = el[sid] + er[b * 256 + d2];
        tv = tv > 0.f ? tv : 0.2f * tv;       // leaky_relu; |tv| small -> exp exact-safe
        float ex = __expf(tv);
        int p = atomicAdd(&cur[d2], 1);
        if (p < OBCAP) { obuf[p] = e; exb[p] = ex; }
        atomicAdd(&ssl[d2], ex);
    }
    __syncthreads();
    for (int i = t; i < cnt; i += 256) {
        unsigned e = obuf[i];
        float alpha = exb[i] / ssl[e >> 17];
        exs[base + i] = make_float2(alpha, __uint_as_float((e & 0x1FFFFu) << 8));
    }
}

// ---------------- fused: normalized aggregation + head ----------------
__global__ __launch_bounds__(256) void agg_fused(const int* __restrict__ rowptr,
                                                 const int* __restrict__ deg,
                                                 const float2* __restrict__ exs,
                                                 const char* __restrict__ Hc,
                                                 const float* __restrict__ bias,
                                                 const float* __restrict__ fcw,
                                                 const float* __restrict__ fcb,
                                                 float* __restrict__ out) {
    __shared__ float2 exbuf[4][64];
    int tid   = threadIdx.x;
    int wslot = tid >> 6;
    int wid   = (blockIdx.x * 256 + tid) >> 6;
    int lane  = tid & 63;
    if (wid >= N_NODES) return;
    int grp = lane >> 4, fl = lane & 15;
    int start = rowptr[wid];
    int dg    = deg[wid];
    float acc[8] = {};
    float2* eb = exbuf[wslot];
    unsigned flb = (unsigned)fl << 4;

    for (int base = 0; base < dg; base += 64) {
        int cnt = min(64, dg - base);
        float2 p2 = make_float2(0.f, 0.f);     // alpha=0, row 0 -> harmless pad
        if (lane < cnt) p2 = exs[start + base + lane];
        eb[lane] = p2;
        __builtin_amdgcn_wave_barrier();
        int nq = (cnt + 3) >> 2;
        #pragma unroll 2
        for (int q = 0; q < nq; ++q) {
            float2 p = eb[q * 4 + grp];
            float aq = p.x;
            uint4 v = *(const uint4*)(Hc + (__float_as_uint(p.y) + flb));
            acc[0] += aq * __uint_as_float(v.x << 16);
            acc[1] += aq * __uint_as_float(v.x & 0xffff0000u);
            acc[2] += aq * __uint_as_float(v.y << 16);
            acc[3] += aq * __uint_as_float(v.y & 0xffff0000u);
            acc[4] += aq * __uint_as_float(v.z << 16);
            acc[5] += aq * __uint_as_float(v.z & 0xffff0000u);
            acc[6] += aq * __uint_as_float(v.w << 16);
            acc[7] += aq * __uint_as_float(v.w & 0xffff0000u);
        }
        __builtin_amdgcn_wave_barrier();
    }

    #pragma unroll
    for (int j = 0; j < 8; ++j) {
        acc[j] += __shfl_xor(acc[j], 16);
        acc[j] += __shfl_xor(acc[j], 32);
    }

    float4 b0 = ((const float4*)bias)[fl * 2];
    float4 b1 = ((const float4*)bias)[fl * 2 + 1];
    float d0 = 0.f, d1 = 0.f;
    #pragma unroll
    for (int j = 0; j < 8; ++j) {
        float bj = j < 4 ? (&b0.x)[j] : (&b1.x)[j - 4];
        float vv = fmaxf(acc[j] + bj, 0.f);
        float2 wj = ((const float2*)fcw)[fl * 8 + j];
        d0 += vv * wj.x;
        d1 += vv * wj.y;
    }
    #pragma unroll
    for (int off = 1; off < 16; off <<= 1) {
        d0 += __shfl_xor(d0, off);
        d1 += __shfl_xor(d1, off);
    }
    if (lane == 0) {
        out[(size_t)wid * 2 + 0] = 1.f / (1.f + __expf(-(d0 + fcb[0])));
        out[(size_t)wid * 2 + 1] = 1.f / (1.f + __expf(-(d1 + fcb[1])));
    }
}

extern "C" void kernel_launch(void* const* d_in, const int* in_sizes, int n_in,
                              void* d_out, int out_size, void* d_ws, size_t ws_size,
                              hipStream_t stream) {
    const float* in_feat = (const float*)d_in[0];
    const float* W       = (const float*)d_in[1];
    const float* attn_l  = (const float*)d_in[2];
    const float* attn_r  = (const float*)d_in[3];
    const float* bias    = (const float*)d_in[4];
    const float* fc_w    = (const float*)d_in[5];
    const float* fc_b    = (const float*)d_in[6];
    const int*   src     = (const int*)d_in[7];
    const int*   dst     = (const int*)d_in[8];
    float* out = (float*)d_out;

    char* p = (char*)d_ws;
    unsigned short* HB = (unsigned short*)p; p += (size_t)N_NODES * F_OUT * sizeof(unsigned short);
    unsigned short* WT = (unsigned short*)p; p += (size_t)F_IN * F_OUT * sizeof(unsigned short);
    float* EL     = (float*)p; p += (size_t)N_NODES * sizeof(float);
    float* ER     = (float*)p; p += (size_t)N_NODES * sizeof(float);
    int*   DEG    = (int*)p;   p += (size_t)N_NODES * sizeof(int);
    int*   ROWPTR = (int*)p;   p += (size_t)N_NODES * sizeof(int);
    int*   BCNT   = (int*)p;   p += 512 * sizeof(int);
    int*   BBASE  = (int*)p;   p += 512 * sizeof(int);
    int*   HIST   = (int*)p;   p += (size_t)NBKT * HSTR * sizeof(int);
    unsigned int* EPACK = (unsigned int*)p; p += (size_t)E_EDGES * sizeof(unsigned int);
    float2* EXS   = (float2*)p; p += (size_t)E_EDGES * sizeof(float2);

    hipMemsetAsync(BCNT, 0, 512 * sizeof(int), stream);

    wcvt_hist<<<WCVT_NB + NBKT, 256, 0, stream>>>(W, WT, dst, BCNT, HIST);
    k_scan2  <<<NBKT, 512, 0, stream>>>(BCNT, BBASE, HIST);
    gemm_scatter<<<GEMM_NB + NBKT, 256, 0, stream>>>(
        in_feat, WT, attn_l, attn_r, HB, EL, ER, src, dst, HIST, EPACK);
    k_sort2  <<<NBKT, 256, 0, stream>>>(EPACK, BBASE, EL, ER, EXS, ROWPTR, DEG);

    agg_fused<<<(N_NODES * 64 + 255) / 256, 256, 0, stream>>>(
        ROWPTR, DEG, EXS, (const char*)HB, bias, fc_w, fc_b, out);
}